// Round 13
// baseline (181.686 us; speedup 1.0000x reference)
//
#include <hip/hip_runtime.h>
#include <stdint.h>

#define TABLE_MASK 0x7FFFFu          // TABLE_SIZE = 524288 = 2^19
#define PRIME 2654435761u
#define WORDS_PER_TABLE 65536        // 524288 entries * 4 bits / 32
#define CELLS_PER_PLANE (512 * 512)  // 262144 cells, uint16 each

// ---------------------------------------------------------------------------
// Stage 1: binarize three (524288,4) f32 tables into 4-bit nibbles.
// Entry e -> word e>>3, nibble (e&7); bit f set <=> table[e][f] >= 0 (+1).
// ---------------------------------------------------------------------------
__global__ __launch_bounds__(256) void pack_kernel(
    const float* __restrict__ t0, const float* __restrict__ t1,
    const float* __restrict__ t2, uint32_t* __restrict__ out) {
  uint32_t tid = blockIdx.x * 256u + threadIdx.x;   // 0 .. 3*65536-1
  uint32_t tab = tid >> 16;
  uint32_t word = tid & 65535u;
  const float4* t =
      (const float4*)(tab == 0 ? t0 : (tab == 1 ? t1 : t2)) + word * 8u;
  uint32_t v = 0;
#pragma unroll
  for (int k = 0; k < 8; ++k) {
    float4 f = t[k];
    uint32_t n = (f.x >= 0.0f ? 1u : 0u) | (f.y >= 0.0f ? 2u : 0u) |
                 (f.z >= 0.0f ? 4u : 0u) | (f.w >= 0.0f ? 8u : 0u);
    v |= n << (4 * k);
  }
  out[tid] = v;
}

// ---------------------------------------------------------------------------
// Stage 2: per-cell corner records, all 3 planes. Cell (ia,ib) in [0,512)^2:
// bits [0:3]=n(ia,ib) [4:7]=n(ia,ib+1) [8:11]=n(ia+1,ib) [12:15]=n(ia+1,ib+1)
// ---------------------------------------------------------------------------
__global__ __launch_bounds__(256) void cellify_kernel(
    const uint32_t* __restrict__ pk, uint16_t* __restrict__ cells) {
  uint32_t tid = blockIdx.x * 256u + threadIdx.x;   // 0 .. 3*262144-1
  uint32_t plane = tid >> 18;
  uint32_t ia = (tid >> 9) & 511u;
  uint32_t ib = tid & 511u;
  const uint32_t* t = pk + plane * WORDS_PER_TABLE;
  uint32_t hb0 = ib * PRIME;
  uint32_t hb1 = hb0 + PRIME;
  uint32_t i00 = (ia ^ hb0) & TABLE_MASK;
  uint32_t i01 = (ia ^ hb1) & TABLE_MASK;
  uint32_t d = ia ^ (ia + 1u);                      // +x corners share word 7/8
  uint32_t i10 = i00 ^ d;
  uint32_t i11 = i01 ^ d;
  uint32_t w00 = t[i00 >> 3];
  uint32_t w01 = t[i01 >> 3];
  uint32_t w10 = w00, w11 = w01;
  if (d >= 8u) {
    w10 = t[i10 >> 3];
    w11 = t[i11 >> 3];
  }
  uint32_t n00 = (w00 >> ((i00 & 7u) * 4u)) & 15u;
  uint32_t n01 = (w01 >> ((i01 & 7u) * 4u)) & 15u;
  uint32_t n10 = (w10 >> ((i10 & 7u) * 4u)) & 15u;
  uint32_t n11 = (w11 >> ((i11 & 7u) * 4u)) & 15u;
  cells[tid] = (uint16_t)(n00 | (n01 << 4) | (n10 << 8) | (n11 << 12));
}

// ---------------------------------------------------------------------------
// Stage 3: main kernel. 4 points/thread; 12 cell gathers + the vmcnt(0) in a
// SINGLE asm block (no compiler-visible hazard window: outputs become live
// only when the block exits, after the waitcnt). Early-clobber keeps dest
// regs disjoint from address regs (dest writes land async while later loads
// still read their addresses).
// ---------------------------------------------------------------------------
__device__ __forceinline__ float bitmask_w(float w, uint32_t r, int bit) {
  // w if bit set else 0, branch-free: float & sign-extended bit
  return __uint_as_float(__float_as_uint(w) &
                         (uint32_t)__builtin_amdgcn_sbfe((int)r, bit, 1));
}

__device__ __forceinline__ void acc_rec(uint32_t r, float wa, float wb,
                                        float& q0, float& q1, float& q2,
                                        float& q3) {
  float omwa = 1.0f - wa, omwb = 1.0f - wb;
  float v00 = omwa * omwb, v01 = omwa * wb, v10 = wa * omwb, v11 = wa * wb;
  q0 += bitmask_w(v00, r, 0) + bitmask_w(v01, r, 4) + bitmask_w(v10, r, 8) +
        bitmask_w(v11, r, 12);
  q1 += bitmask_w(v00, r, 1) + bitmask_w(v01, r, 5) + bitmask_w(v10, r, 9) +
        bitmask_w(v11, r, 13);
  q2 += bitmask_w(v00, r, 2) + bitmask_w(v01, r, 6) + bitmask_w(v10, r, 10) +
        bitmask_w(v11, r, 14);
  q3 += bitmask_w(v00, r, 3) + bitmask_w(v01, r, 7) + bitmask_w(v10, r, 11) +
        bitmask_w(v11, r, 15);
}

__global__ __launch_bounds__(256, 8) void hash_asm(
    const float4* __restrict__ pos4, const uint16_t* __restrict__ cells,
    float4* __restrict__ out4, int nq) {
  int t = (int)(blockIdx.x * 256u + threadIdx.x);
  if (t >= nq) return;
  float4 A = pos4[3 * t + 0];
  float4 B = pos4[3 * t + 1];
  float4 C = pos4[3 * t + 2];
  float X[4] = {A.x, A.w, B.z, C.y};
  float Y[4] = {A.y, B.x, B.w, C.z};
  float Z[4] = {A.z, B.y, C.x, C.w};

  uint32_t off[12];
#pragma unroll
  for (int k = 0; k < 4; ++k) {
    uint32_t ix = (uint32_t)floorf(X[k] * 512.0f);
    uint32_t iy = (uint32_t)floorf(Y[k] * 512.0f);
    uint32_t iz = (uint32_t)floorf(Z[k] * 512.0f);
    off[3 * k + 0] = ((ix << 9) | iy) * 2u;
    off[3 * k + 1] = (CELLS_PER_PLANE + ((ix << 9) | iz)) * 2u;
    off[3 * k + 2] = (2u * CELLS_PER_PLANE + ((iy << 9) | iz)) * 2u;
  }

  uint32_t R[12];
  // All 12 loads in flight, ONE wait, zero compiler-visible hazard window.
  asm volatile(
      "global_load_ushort %0, %12, %24\n\t"
      "global_load_ushort %1, %13, %24\n\t"
      "global_load_ushort %2, %14, %24\n\t"
      "global_load_ushort %3, %15, %24\n\t"
      "global_load_ushort %4, %16, %24\n\t"
      "global_load_ushort %5, %17, %24\n\t"
      "global_load_ushort %6, %18, %24\n\t"
      "global_load_ushort %7, %19, %24\n\t"
      "global_load_ushort %8, %20, %24\n\t"
      "global_load_ushort %9, %21, %24\n\t"
      "global_load_ushort %10, %22, %24\n\t"
      "global_load_ushort %11, %23, %24\n\t"
      "s_waitcnt vmcnt(0)"
      : "=&v"(R[0]), "=&v"(R[1]), "=&v"(R[2]), "=&v"(R[3]), "=&v"(R[4]),
        "=&v"(R[5]), "=&v"(R[6]), "=&v"(R[7]), "=&v"(R[8]), "=&v"(R[9]),
        "=&v"(R[10]), "=&v"(R[11])
      : "v"(off[0]), "v"(off[1]), "v"(off[2]), "v"(off[3]), "v"(off[4]),
        "v"(off[5]), "v"(off[6]), "v"(off[7]), "v"(off[8]), "v"(off[9]),
        "v"(off[10]), "v"(off[11]), "s"(cells)
      : "memory");

  // Consume (weights recomputed -> low VGPR pressure).
#pragma unroll
  for (int k = 0; k < 4; ++k) {
    float sx = X[k] * 512.0f, sy = Y[k] * 512.0f, sz = Z[k] * 512.0f;
    float wx = sx - floorf(sx);
    float wy = sy - floorf(sy);
    float wz = sz - floorf(sz);
    float q0 = 0.f, q1 = 0.f, q2 = 0.f, q3 = 0.f;
    acc_rec(R[3 * k + 0], wx, wy, q0, q1, q2, q3);
    acc_rec(R[3 * k + 1], wx, wz, q0, q1, q2, q3);
    acc_rec(R[3 * k + 2], wy, wz, q0, q1, q2, q3);
    float4 o;
    o.x = fmaf(2.0f, q0, -3.0f);   // sum over 3 planes of (2*q_plane - 1)
    o.y = fmaf(2.0f, q1, -3.0f);
    o.z = fmaf(2.0f, q2, -3.0f);
    o.w = fmaf(2.0f, q3, -3.0f);
    out4[4 * t + k] = o;
  }
}

// Scalar tail kernel (n % 4 != 0).
__global__ __launch_bounds__(256) void hash_tail(
    const float* __restrict__ pos, const uint16_t* __restrict__ cells,
    float4* __restrict__ out, int n, int start) {
  int i = start + (int)(blockIdx.x * 256u + threadIdx.x);
  if (i >= n) return;
  float x = pos[3 * i + 0];
  float y = pos[3 * i + 1];
  float z = pos[3 * i + 2];
  float q0 = 0.f, q1 = 0.f, q2 = 0.f, q3 = 0.f;
  float sx = x * 512.0f, sy = y * 512.0f, sz = z * 512.0f;
  float fx = floorf(sx), fy = floorf(sy), fz = floorf(sz);
  uint32_t ix = (uint32_t)fx, iy = (uint32_t)fy, iz = (uint32_t)fz;
  acc_rec(cells[(ix << 9) | iy], sx - fx, sy - fy, q0, q1, q2, q3);
  acc_rec(cells[CELLS_PER_PLANE + ((ix << 9) | iz)], sx - fx, sz - fz, q0, q1,
          q2, q3);
  acc_rec(cells[2 * CELLS_PER_PLANE + ((iy << 9) | iz)], sy - fy, sz - fz, q0,
          q1, q2, q3);
  float4 o;
  o.x = fmaf(2.0f, q0, -3.0f);
  o.y = fmaf(2.0f, q1, -3.0f);
  o.z = fmaf(2.0f, q2, -3.0f);
  o.w = fmaf(2.0f, q3, -3.0f);
  out[i] = o;
}

// ---------------------------------------------------------------------------
// Fallback (ws too small): gather f32 features directly, binarize on the fly.
// ---------------------------------------------------------------------------
__device__ __forceinline__ void plane_accum_f(
    const float4* __restrict__ t, float a, float b,
    float& p0, float& p1, float& p2, float& p3) {
  float sa = a * 512.0f, sb = b * 512.0f;
  float fa = floorf(sa), fb = floorf(sb);
  float wa = sa - fa, wb = sb - fb;
  uint32_t ia = (uint32_t)fa, ib = (uint32_t)fb;
  uint32_t hb0 = ib * PRIME;
  uint32_t hb1 = hb0 + PRIME;
  uint32_t i00 = (ia ^ hb0) & TABLE_MASK;
  uint32_t i01 = (ia ^ hb1) & TABLE_MASK;
  uint32_t i10 = ((ia + 1u) ^ hb0) & TABLE_MASK;
  uint32_t i11 = ((ia + 1u) ^ hb1) & TABLE_MASK;
  float4 f00 = t[i00], f01 = t[i01], f10 = t[i10], f11 = t[i11];
  float omwa = 1.0f - wa, omwb = 1.0f - wb;
  float v00 = omwa * omwb, v01 = omwa * wb, v10 = wa * omwb, v11 = wa * wb;
#define ACCF(F, W)                                                            \
  p0 += ((F).x >= 0.0f) ? (W) : 0.0f;                                         \
  p1 += ((F).y >= 0.0f) ? (W) : 0.0f;                                         \
  p2 += ((F).z >= 0.0f) ? (W) : 0.0f;                                         \
  p3 += ((F).w >= 0.0f) ? (W) : 0.0f;
  ACCF(f00, v00)
  ACCF(f01, v01)
  ACCF(f10, v10)
  ACCF(f11, v11)
#undef ACCF
}

__global__ __launch_bounds__(256) void hash_direct(
    const float* __restrict__ pos, const float4* __restrict__ txy,
    const float4* __restrict__ txz, const float4* __restrict__ tyz,
    float4* __restrict__ out, int n) {
  int i = (int)(blockIdx.x * 256u + threadIdx.x);
  if (i >= n) return;
  float x = pos[3 * i + 0];
  float y = pos[3 * i + 1];
  float z = pos[3 * i + 2];
  float p0 = 0.f, p1 = 0.f, p2 = 0.f, p3 = 0.f;
  plane_accum_f(txy, x, y, p0, p1, p2, p3);
  plane_accum_f(txz, x, z, p0, p1, p2, p3);
  plane_accum_f(tyz, y, z, p0, p1, p2, p3);
  float4 o;
  o.x = fmaf(2.0f, p0, -3.0f);
  o.y = fmaf(2.0f, p1, -3.0f);
  o.z = fmaf(2.0f, p2, -3.0f);
  o.w = fmaf(2.0f, p3, -3.0f);
  out[i] = o;
}

extern "C" void kernel_launch(void* const* d_in, const int* in_sizes, int n_in,
                              void* d_out, int out_size, void* d_ws,
                              size_t ws_size, hipStream_t stream) {
  const float* pos = (const float*)d_in[0];
  const float* txy = (const float*)d_in[1];
  const float* txz = (const float*)d_in[2];
  const float* tyz = (const float*)d_in[3];
  float4* out = (float4*)d_out;
  int n = in_sizes[0] / 3;                       // 4194304
  const size_t pk_bytes = (size_t)3 * WORDS_PER_TABLE * 4;        // 768 KB
  const size_t cell_bytes = (size_t)3 * CELLS_PER_PLANE * 2;      // 1.5 MB
  if (ws_size >= pk_bytes + cell_bytes) {
    uint32_t* pk = (uint32_t*)d_ws;
    uint16_t* cells = (uint16_t*)((char*)d_ws + pk_bytes);
    pack_kernel<<<3 * WORDS_PER_TABLE / 256, 256, 0, stream>>>(txy, txz, tyz,
                                                               pk);
    cellify_kernel<<<3 * CELLS_PER_PLANE / 256, 256, 0, stream>>>(pk, cells);
    int nq = n / 4;
    if (nq > 0)
      hash_asm<<<(nq + 255) / 256, 256, 0, stream>>>((const float4*)pos,
                                                     cells, out, nq);
    int rem = n - nq * 4;
    if (rem > 0)
      hash_tail<<<(rem + 255) / 256, 256, 0, stream>>>(pos, cells, out, n,
                                                       nq * 4);
  } else {
    hash_direct<<<(n + 255) / 256, 256, 0, stream>>>(
        pos, (const float4*)txy, (const float4*)txz, (const float4*)tyz, out,
        n);
  }
}